// Round 1
// 29180.786 us; speedup vs baseline: 1.2347x; 1.2347x over previous
//
#include <hip/hip_runtime.h>
#include <math.h>

typedef unsigned short ushort_t;
typedef short short8 __attribute__((ext_vector_type(8)));
typedef float floatx4 __attribute__((ext_vector_type(4)));
typedef float float4v __attribute__((ext_vector_type(4)));

__device__ __forceinline__ float b2f(ushort_t u) {
    union { unsigned int i; float f; } v; v.i = ((unsigned int)u) << 16; return v.f;
}
__device__ __forceinline__ ushort_t f2b(float f) {
    union { float f; unsigned int i; } v; v.f = f;
    unsigned int x = v.i;
    return (ushort_t)((x + 0x7fffu + ((x >> 16) & 1u)) >> 16);  // RNE
}
__device__ __forceinline__ void split8(const float* v, short8& hi, short8& lo) {
#pragma unroll
    for (int e = 0; e < 8; ++e) {
        ushort_t h = f2b(v[e]);
        hi[e] = (short)h;
        lo[e] = (short)f2b(v[e] - b2f(h));
    }
}
__device__ __forceinline__ void load8f(const float* p, float* v) {
    *(float4v*)(v)     = *(const float4v*)(p);
    *(float4v*)(v + 4) = *(const float4v*)(p + 4);
}
__device__ __forceinline__ floatx4 mfma16(short8 a, short8 b, floatx4 c) {
    return __builtin_amdgcn_mfma_f32_16x16x32_bf16(a, b, c, 0, 0, 0);
}

// Classify input encoding (fallback when in_sizes doesn't resolve it).
__global__ void detect_dtype(const unsigned int* __restrict__ x, int* __restrict__ flag) {
    __shared__ int cnt;
    if (threadIdx.x == 0) cnt = 0;
    __syncthreads();
    int c = 0;
#pragma unroll
    for (int i = 0; i < 8; ++i) {
        unsigned int w = x[threadIdx.x * 8 + i];
        unsigned int e = (w >> 7) & 0xFFu;
        if (e >= 100u && e <= 140u) ++c;
    }
    atomicAdd(&cnt, c);
    __syncthreads();
    if (threadIdx.x == 0) *flag = (cnt > 1024) ? 1 : 0;   // 1 = bf16, 0 = f32
}

// One-time parallel pre-split:
//  XS (into d_out scratch): masked X as interleaved [hi8|lo8] bf16 chunks, layout (t*32+b)
//  WS1 (into ws): W_ih_l1 as interleaved [hi8|lo8] chunks, layout row-major
__global__ __launch_bounds__(256) void prep(
    const int* __restrict__ flag,
    const void* __restrict__ x, const void* __restrict__ mask_x,
    const void* __restrict__ w_ih_l1,
    char* __restrict__ xs, char* __restrict__ ws1, int have_ws1)
{
    const bool isbf = (*flag != 0);
    const int i = blockIdx.x * 256 + threadIdx.x;
    if (i < 1048576) {                       // 32 b * 512 t * 64 chunks
        const int b = i >> 15;
        const int rem = i & 32767;
        const int t = rem >> 6;
        const int c = rem & 63;
        const size_t xoff = ((size_t)(b * 512 + t)) * 512 + c * 8;
        if (isbf) {
            const ushort_t* X = (const ushort_t*)x;
            const ushort_t* M = (const ushort_t*)mask_x + b * 512 + c * 8;
            short8 o;
#pragma unroll
            for (int e = 0; e < 8; ++e) o[e] = (short)f2b(b2f(X[xoff + e]) * b2f(M[e]));
            *(short8*)(xs + ((size_t)t * 32 + b) * 1024 + c * 16) = o;
        } else {
            float v[8], m[8];
            load8f((const float*)x + xoff, v);
            load8f((const float*)mask_x + b * 512 + c * 8, m);
#pragma unroll
            for (int e = 0; e < 8; ++e) v[e] *= m[e];
            short8 hi, lo; split8(v, hi, lo);
            char* p = xs + ((size_t)t * 32 + b) * 2048 + c * 32;
            *(short8*)p = hi; *(short8*)(p + 16) = lo;
        }
    } else if (have_ws1 && !isbf) {          // 4096 rows * 128 chunks
        const int jj = i - 1048576;
        const int row = jj >> 7;
        const int c = jj & 127;
        float v[8];
        load8f((const float*)w_ih_l1 + (size_t)row * 1024 + c * 8, v);
        short8 hi, lo; split8(v, hi, lo);
        char* p = ws1 + (size_t)row * 4096 + c * 32;
        *(short8*)p = hi; *(short8*)(p + 16) = lo;
    }
}

// Persistent per-layer LSTM: 64 blocks (32 per direction) x 256 thr, all 512
// timesteps inside one launch. Device-scope sense counter per direction.
// Weights register-resident (L0: W_ih+W_hh, L1: W_hh; W_ih_l1 streamed from
// pre-split WS1). h exchanged via global hi/lo buffer; c stays in registers.
template <int LAYER>
__global__ __launch_bounds__(256, 1) void lstm_phase(
    const int* __restrict__ flag,
    const char* __restrict__ xs,     // L0: XS (in d_out); L1: OS (in ws)
    char* __restrict__ os,           // L0 output region (ws); unused for L1
    const char* __restrict__ ws1c,   // pre-split W_ih_l1 (or null)
    char* __restrict__ hs,           // h double buffer [par][d][b] * 2048B
    unsigned int* cnt,               // arrival counters, cnt[0] / cnt[32]
    const void* __restrict__ w_ih, const void* __restrict__ w_hh,
    const void* __restrict__ bias, const void* __restrict__ mask_h,
    const void* __restrict__ mask_out, void* __restrict__ dout,
    int os4_host, int have_ws1, int write_hn)
{
    __shared__ float gbuf[4][32][16];
    const int d    = blockIdx.x >> 5;
    const int j0   = (blockIdx.x & 31) << 4;
    const int tid  = threadIdx.x;
    const int lane = tid & 63;
    const int q    = tid >> 6;
    const int n16  = lane & 15;
    const int quad = lane >> 4;
    const int koff = quad * 8;
    const int g    = q * 512 + j0 + n16;
    const bool isbf = (*flag != 0);
    const bool os4  = (!isbf) && (os4_host != 0);
    unsigned int* mycnt = cnt + d * 32;

    // ---- one-time: W_hh slice -> registers (16 chunks hi/lo) ----
    short8 whh_h[16], whh_l[16];
    if (isbf) {
        const ushort_t* W = (const ushort_t*)w_hh + ((size_t)(d * 2048 + g)) * 512 + koff;
#pragma unroll
        for (int ki = 0; ki < 16; ++ki) {
            whh_h[ki] = *(const short8*)(W + ki * 32);
            whh_l[ki] = short8{0,0,0,0,0,0,0,0};
        }
    } else {
        const float* W = (const float*)w_hh + ((size_t)(d * 2048 + g)) * 512 + koff;
#pragma unroll
        for (int ki = 0; ki < 16; ++ki) {
            float w8[8]; load8f(W + ki * 32, w8);
            split8(w8, whh_h[ki], whh_l[ki]);
        }
    }
    // ---- one-time (L0): W_ih slice -> registers ----
    short8 wih_h[16], wih_l[16];
    if constexpr (LAYER == 0) {
        if (isbf) {
            const ushort_t* W = (const ushort_t*)w_ih + ((size_t)(d * 2048 + g)) * 512 + koff;
#pragma unroll
            for (int ki = 0; ki < 16; ++ki) {
                wih_h[ki] = *(const short8*)(W + ki * 32);
                wih_l[ki] = short8{0,0,0,0,0,0,0,0};
            }
        } else {
            const float* W = (const float*)w_ih + ((size_t)(d * 2048 + g)) * 512 + koff;
#pragma unroll
            for (int ki = 0; ki < 16; ++ki) {
                float w8[8]; load8f(W + ki * 32, w8);
                split8(w8, wih_h[ki], wih_l[ki]);
            }
        }
    }

    // ---- one-time: biases / masks for the epilogue -> registers ----
    float pbi[2], pbf[2], pbg[2], pbo[2], pmh[2], pmo[2];
#pragma unroll
    for (int rep = 0; rep < 2; ++rep) {
        const int idx = tid + rep * 256;
        const int b = idx >> 4;
        const int j = j0 + (idx & 15);
        if (isbf) {
            const ushort_t* BI = (const ushort_t*)bias;
            const ushort_t* MH = (const ushort_t*)mask_h + LAYER * 16384;
            pbi[rep] = b2f(BI[d * 2048 + j]);        pbf[rep] = b2f(BI[d * 2048 + 512 + j]);
            pbg[rep] = b2f(BI[d * 2048 + 1024 + j]); pbo[rep] = b2f(BI[d * 2048 + 1536 + j]);
            pmh[rep] = b2f(MH[b * 512 + j]);
            if constexpr (LAYER == 0) pmo[rep] = b2f(((const ushort_t*)mask_out)[b * 1024 + d * 512 + j]);
            else pmo[rep] = 0.f;
        } else {
            const float* BI = (const float*)bias;
            const float* MH = (const float*)mask_h + LAYER * 16384;
            pbi[rep] = BI[d * 2048 + j];        pbf[rep] = BI[d * 2048 + 512 + j];
            pbg[rep] = BI[d * 2048 + 1024 + j]; pbo[rep] = BI[d * 2048 + 1536 + j];
            pmh[rep] = MH[b * 512 + j];
            if constexpr (LAYER == 0) pmo[rep] = ((const float*)mask_out)[b * 1024 + d * 512 + j];
            else pmo[rep] = 0.f;
        }
    }
    float creg[2] = {0.f, 0.f};   // cell state lives in registers

    for (int s = 0; s < 512; ++s) {
        const int t = d ? (511 - s) : s;
        floatx4 acc0 = {0.f, 0.f, 0.f, 0.f};
        floatx4 acc1 = {0.f, 0.f, 0.f, 0.f};

        // ================= x-part (independent of h; before barrier) =========
        if constexpr (LAYER == 0) {
            if (isbf) {
                const char* xb0 = xs + ((size_t)t * 32 + n16) * 1024 + quad * 16;
                const char* xb1 = xs + ((size_t)t * 32 + n16 + 16) * 1024 + quad * 16;
#pragma unroll
                for (int ki = 0; ki < 16; ++ki) {
                    short8 a0 = *(const short8*)(xb0 + ki * 64);
                    short8 a1 = *(const short8*)(xb1 + ki * 64);
                    acc0 = mfma16(a0, wih_h[ki], acc0);
                    acc1 = mfma16(a1, wih_h[ki], acc1);
                }
            } else {
                const char* xb0 = xs + ((size_t)t * 32 + n16) * 2048 + quad * 32;
                const char* xb1 = xs + ((size_t)t * 32 + n16 + 16) * 2048 + quad * 32;
#pragma unroll
                for (int ki = 0; ki < 16; ++ki) {
                    short8 a0h = *(const short8*)(xb0 + ki * 128);
                    short8 a0l = *(const short8*)(xb0 + ki * 128 + 16);
                    short8 a1h = *(const short8*)(xb1 + ki * 128);
                    short8 a1l = *(const short8*)(xb1 + ki * 128 + 16);
                    acc0 = mfma16(a0h, wih_h[ki], acc0);
                    acc0 = mfma16(a0l, wih_h[ki], acc0);
                    acc0 = mfma16(a0h, wih_l[ki], acc0);
                    acc1 = mfma16(a1h, wih_h[ki], acc1);
                    acc1 = mfma16(a1l, wih_h[ki], acc1);
                    acc1 = mfma16(a1h, wih_l[ki], acc1);
                }
            }
        } else {
            const size_t wrow = (size_t)d * 2048 + g;
            if (isbf) {
                const ushort_t* W = (const ushort_t*)w_ih + wrow * 1024 + koff;
                const char* ab0 = xs + ((size_t)t * 32 + n16) * 2048 + quad * 16;
                const char* ab1 = xs + ((size_t)t * 32 + n16 + 16) * 2048 + quad * 16;
#pragma unroll 4
                for (int ki = 0; ki < 32; ++ki) {
                    short8 a0 = *(const short8*)(ab0 + ki * 64);
                    short8 a1 = *(const short8*)(ab1 + ki * 64);
                    short8 bh = *(const short8*)(W + ki * 32);
                    acc0 = mfma16(a0, bh, acc0);
                    acc1 = mfma16(a1, bh, acc1);
                }
            } else if (have_ws1) {
                const char* wb = ws1c + wrow * 4096 + quad * 32;
                if (os4) {
                    const char* ab0 = xs + ((size_t)t * 32 + n16) * 4096 + quad * 32;
                    const char* ab1 = xs + ((size_t)t * 32 + n16 + 16) * 4096 + quad * 32;
#pragma unroll 4
                    for (int ki = 0; ki < 32; ++ki) {
                        short8 bh  = *(const short8*)(wb + ki * 128);
                        short8 bl  = *(const short8*)(wb + ki * 128 + 16);
                        short8 a0h = *(const short8*)(ab0 + ki * 128);
                        short8 a0l = *(const short8*)(ab0 + ki * 128 + 16);
                        short8 a1h = *(const short8*)(ab1 + ki * 128);
                        short8 a1l = *(const short8*)(ab1 + ki * 128 + 16);
                        acc0 = mfma16(a0h, bh, acc0);
                        acc0 = mfma16(a0l, bh, acc0);
                        acc0 = mfma16(a0h, bl, acc0);
                        acc1 = mfma16(a1h, bh, acc1);
                        acc1 = mfma16(a1l, bh, acc1);
                        acc1 = mfma16(a1h, bl, acc1);
                    }
                } else {    // compact OS: a_lo == 0 exactly -> skip its MFMA
                    const char* ab0 = xs + ((size_t)t * 32 + n16) * 2048 + quad * 16;
                    const char* ab1 = xs + ((size_t)t * 32 + n16 + 16) * 2048 + quad * 16;
#pragma unroll 4
                    for (int ki = 0; ki < 32; ++ki) {
                        short8 bh = *(const short8*)(wb + ki * 128);
                        short8 bl = *(const short8*)(wb + ki * 128 + 16);
                        short8 a0 = *(const short8*)(ab0 + ki * 64);
                        short8 a1 = *(const short8*)(ab1 + ki * 64);
                        acc0 = mfma16(a0, bh, acc0);
                        acc0 = mfma16(a0, bl, acc0);
                        acc1 = mfma16(a1, bh, acc1);
                        acc1 = mfma16(a1, bl, acc1);
                    }
                }
            } else {        // floor tier: split W_ih_l1 in-loop (slow, rare)
                const float* wf = (const float*)w_ih + wrow * 1024 + koff;
                if (os4) {
                    const char* ab0 = xs + ((size_t)t * 32 + n16) * 4096 + quad * 32;
                    const char* ab1 = xs + ((size_t)t * 32 + n16 + 16) * 4096 + quad * 32;
#pragma unroll 4
                    for (int ki = 0; ki < 32; ++ki) {
                        float w8[8]; load8f(wf + ki * 32, w8);
                        short8 bh, bl; split8(w8, bh, bl);
                        short8 a0h = *(const short8*)(ab0 + ki * 128);
                        short8 a0l = *(const short8*)(ab0 + ki * 128 + 16);
                        short8 a1h = *(const short8*)(ab1 + ki * 128);
                        short8 a1l = *(const short8*)(ab1 + ki * 128 + 16);
                        acc0 = mfma16(a0h, bh, acc0);
                        acc0 = mfma16(a0l, bh, acc0);
                        acc0 = mfma16(a0h, bl, acc0);
                        acc1 = mfma16(a1h, bh, acc1);
                        acc1 = mfma16(a1l, bh, acc1);
                        acc1 = mfma16(a1h, bl, acc1);
                    }
                } else {
                    const char* ab0 = xs + ((size_t)t * 32 + n16) * 2048 + quad * 16;
                    const char* ab1 = xs + ((size_t)t * 32 + n16 + 16) * 2048 + quad * 16;
#pragma unroll 4
                    for (int ki = 0; ki < 32; ++ki) {
                        float w8[8]; load8f(wf + ki * 32, w8);
                        short8 bh, bl; split8(w8, bh, bl);
                        short8 a0 = *(const short8*)(ab0 + ki * 64);
                        short8 a1 = *(const short8*)(ab1 + ki * 64);
                        acc0 = mfma16(a0, bh, acc0);
                        acc0 = mfma16(a0, bl, acc0);
                        acc1 = mfma16(a1, bh, acc1);
                        acc1 = mfma16(a1, bl, acc1);
                    }
                }
            }
        }

        // ================= wait for h(s-1) from all 32 sibling blocks ========
        if (tid == 0) {
            const unsigned int target = 32u * (unsigned int)s;
            while (__hip_atomic_load(mycnt, __ATOMIC_RELAXED, __HIP_MEMORY_SCOPE_AGENT) < target) { }
        }
        __syncthreads();
        __builtin_amdgcn_fence(__ATOMIC_ACQUIRE, "agent");   // invalidate stale h lines

        // ================= h-part (register-resident W_hh) ===================
        {
            const char* hb  = hs + (size_t)(((s & 1) * 2 + d) * 32) * 2048 + quad * 32;
            const char* h0p = hb + (size_t)n16 * 2048;
            const char* h1p = hb + (size_t)(n16 + 16) * 2048;
            if (isbf) {
#pragma unroll
                for (int ki = 0; ki < 16; ++ki) {
                    short8 a0 = *(const short8*)(h0p + ki * 128);
                    short8 a1 = *(const short8*)(h1p + ki * 128);
                    acc0 = mfma16(a0, whh_h[ki], acc0);
                    acc1 = mfma16(a1, whh_h[ki], acc1);
                }
            } else {
#pragma unroll
                for (int ki = 0; ki < 16; ++ki) {
                    short8 a0h = *(const short8*)(h0p + ki * 128);
                    short8 a0l = *(const short8*)(h0p + ki * 128 + 16);
                    short8 a1h = *(const short8*)(h1p + ki * 128);
                    short8 a1l = *(const short8*)(h1p + ki * 128 + 16);
                    acc0 = mfma16(a0h, whh_h[ki], acc0);
                    acc0 = mfma16(a0l, whh_h[ki], acc0);
                    acc0 = mfma16(a0h, whh_l[ki], acc0);
                    acc1 = mfma16(a1h, whh_h[ki], acc1);
                    acc1 = mfma16(a1l, whh_h[ki], acc1);
                    acc1 = mfma16(a1h, whh_l[ki], acc1);
                }
            }
        }

        // ================= gate exchange + epilogue ==========================
#pragma unroll
        for (int r = 0; r < 4; ++r) {
            gbuf[q][quad * 4 + r][n16]      = acc0[r];
            gbuf[q][16 + quad * 4 + r][n16] = acc1[r];
        }
        __syncthreads();

#pragma unroll
        for (int rep = 0; rep < 2; ++rep) {
            const int idx = tid + rep * 256;
            const int b = idx >> 4;
            const int n = idx & 15;
            const int j = j0 + n;
            const int jg = d * 512 + j;
            float ig = gbuf[0][b][n] + pbi[rep];
            float fg = gbuf[1][b][n] + pbf[rep];
            float gg = gbuf[2][b][n] + pbg[rep];
            float og = gbuf[3][b][n] + pbo[rep];
            float si = 1.f / (1.f + expf(-ig));
            float sf = 1.f / (1.f + expf(-fg));
            float so = 1.f / (1.f + expf(-og));
            float cn = sf * creg[rep] + si * tanhf(gg);
            float h  = so * tanhf(cn);
            creg[rep] = cn;

            float hm = h * pmh[rep];
            char* hw = hs + (size_t)((((s + 1) & 1) * 2 + d) * 32 + b) * 2048 + (j >> 3) * 32 + (j & 7) * 2;
            if (isbf) {
                *(ushort_t*)hw = f2b(hm);
            } else {
                ushort_t hhi = f2b(hm);
                *(ushort_t*)hw        = hhi;
                *(ushort_t*)(hw + 16) = f2b(hm - b2f(hhi));
            }
            if constexpr (LAYER == 0) {
                float ho = h * pmo[rep];
                if (os4) {
                    char* op = os + ((size_t)t * 32 + b) * 4096 + (jg >> 3) * 32 + (jg & 7) * 2;
                    ushort_t ohi = f2b(ho);
                    *(ushort_t*)op        = ohi;
                    *(ushort_t*)(op + 16) = f2b(ho - b2f(ohi));
                } else {
                    *(ushort_t*)(os + ((size_t)t * 32 + b) * 2048 + (size_t)jg * 2) = f2b(ho);
                }
            } else {
                size_t o1 = ((size_t)b * 512 + t) * 1024 + jg;
                if (isbf) ((ushort_t*)dout)[o1] = f2b(h);
                else      ((float*)dout)[o1]    = h;
            }
            if (s == 511 && write_hn) {
                size_t hnidx = 16777216u + (size_t)((LAYER * 2 + d) * 32 + b) * 512 + j;
                if (isbf) { ((ushort_t*)dout)[hnidx] = f2b(h); ((ushort_t*)dout)[hnidx + 65536] = f2b(cn); }
                else      { ((float*)dout)[hnidx]    = h;      ((float*)dout)[hnidx + 65536]    = cn; }
            }
        }
        __syncthreads();                         // all h/out stores drained
        if (tid == 0) {
            __builtin_amdgcn_fence(__ATOMIC_RELEASE, "agent");   // push to LLC
            __hip_atomic_fetch_add(mycnt, 1u, __ATOMIC_RELAXED, __HIP_MEMORY_SCOPE_AGENT);
        }
    }
}

extern "C" void kernel_launch(void* const* d_in, const int* in_sizes, int n_in,
                              void* d_out, int out_size, void* d_ws, size_t ws_size,
                              hipStream_t stream) {
    char* ws = (char*)d_ws;
    const size_t HSB = 262144;   // h double-buffer: [2 par][2 d][32 b] * 2048B
    // ws layout: [OS (67.1MB full | 33.5MB compact)][WS1 16.8MB?][HS][cnt 256][flag 4]
    int os4 = 0, hws1 = 0;
    size_t osb;
    if      (ws_size >= 67108864ull + 16777216ull + HSB + 512) { os4 = 1; hws1 = 1; osb = 67108864ull; }
    else if (ws_size >= 67108864ull + HSB + 512)               { os4 = 1; hws1 = 0; osb = 67108864ull; }
    else if (ws_size >= 33554432ull + 16777216ull + HSB + 512) { os4 = 0; hws1 = 1; osb = 33554432ull; }
    else                                                       { os4 = 0; hws1 = 0; osb = 33554432ull; }
    char* ws1 = ws + osb;
    char* hs  = ws1 + (hws1 ? 16777216 : 0);
    unsigned int* cnt = (unsigned int*)(hs + HSB);
    int* flag = (int*)(hs + HSB + 256);
    int write_hn = (out_size >= 16908288) ? 1 : 0;

    // dtype from input byte size when unambiguous; sniff otherwise.
    int hb = -1;
    if (in_sizes && n_in > 0) {
        if (in_sizes[0] == 33554432) hb = 0;        // f32 x [32,512,512]
        else if (in_sizes[0] == 16777216) hb = 1;   // bf16
    }

    hipMemsetAsync(hs, 0, HSB + 512, stream);       // h=0, cnt=0, flag=0
    if (hb == 1)       hipMemsetAsync(flag, 1, 4, stream);   // nonzero -> bf16
    else if (hb == -1) detect_dtype<<<1, 256, 0, stream>>>((const unsigned int*)d_in[0], flag);

    // Pre-split masked X (scratch in d_out) and W_ih_l1 (ws).
    prep<<<6144, 256, 0, stream>>>(flag, d_in[0], d_in[1], d_in[7],
                                   (char*)d_out, hws1 ? ws1 : nullptr, hws1);

    // Layer 0: persistent, 512 steps with device barrier per step.
    lstm_phase<0><<<64, 256, 0, stream>>>(flag, (const char*)d_out, ws, nullptr,
        hs, cnt, d_in[4], d_in[5], d_in[6], d_in[3], d_in[2], d_out,
        os4, hws1, write_hn);

    hipMemsetAsync(hs, 0, HSB + 256, stream);       // reset h + cnt, keep flag

    // Layer 1: persistent; reads OS (+ pre-split W_ih_l1), writes d_out.
    lstm_phase<1><<<64, 256, 0, stream>>>(flag, (const char*)ws, ws, hws1 ? ws1 : nullptr,
        hs, cnt, d_in[7], d_in[8], d_in[9], d_in[3], nullptr, d_out,
        os4, hws1, write_hn);
}

// Round 2
// 24541.307 us; speedup vs baseline: 1.4681x; 1.1890x over previous
//
#include <hip/hip_runtime.h>
#include <math.h>

typedef unsigned short ushort_t;
typedef short short8 __attribute__((ext_vector_type(8)));
typedef float floatx4 __attribute__((ext_vector_type(4)));
typedef float float4v __attribute__((ext_vector_type(4)));

__device__ __forceinline__ float b2f(ushort_t u) {
    union { unsigned int i; float f; } v; v.i = ((unsigned int)u) << 16; return v.f;
}
__device__ __forceinline__ ushort_t f2b(float f) {
    union { float f; unsigned int i; } v; v.f = f;
    unsigned int x = v.i;
    return (ushort_t)((x + 0x7fffu + ((x >> 16) & 1u)) >> 16);  // RNE
}
__device__ __forceinline__ void split8(const float* v, short8& hi, short8& lo) {
#pragma unroll
    for (int e = 0; e < 8; ++e) {
        ushort_t h = f2b(v[e]);
        hi[e] = (short)h;
        lo[e] = (short)f2b(v[e] - b2f(h));
    }
}
__device__ __forceinline__ void load8f(const float* p, float* v) {
    *(float4v*)(v)     = *(const float4v*)(p);
    *(float4v*)(v + 4) = *(const float4v*)(p + 4);
}
__device__ __forceinline__ floatx4 mfma16(short8 a, short8 b, floatx4 c) {
    return __builtin_amdgcn_mfma_f32_16x16x32_bf16(a, b, c, 0, 0, 0);
}
// Coherent (LLC) 2-byte store: bypass L1/L2 so remote XCDs can read it.
__device__ __forceinline__ void store2_cc(void* p, ushort_t v) {
    asm volatile("global_store_short %0, %1, off sc0 sc1"
                 :: "v"(p), "v"((unsigned int)v) : "memory");
}

// Classify input encoding (fallback when in_sizes doesn't resolve it).
__global__ void detect_dtype(const unsigned int* __restrict__ x, int* __restrict__ flag) {
    __shared__ int cnt;
    if (threadIdx.x == 0) cnt = 0;
    __syncthreads();
    int c = 0;
#pragma unroll
    for (int i = 0; i < 8; ++i) {
        unsigned int w = x[threadIdx.x * 8 + i];
        unsigned int e = (w >> 7) & 0xFFu;
        if (e >= 100u && e <= 140u) ++c;
    }
    atomicAdd(&cnt, c);
    __syncthreads();
    if (threadIdx.x == 0) *flag = (cnt > 1024) ? 1 : 0;   // 1 = bf16, 0 = f32
}

// One-time parallel pre-split:
//  XS (into d_out scratch): masked X as interleaved [hi8|lo8] bf16 chunks, layout (t*32+b)
//  WS1 (into ws): W_ih_l1 as interleaved [hi8|lo8] chunks, layout row-major
__global__ __launch_bounds__(256) void prep(
    const int* __restrict__ flag,
    const void* __restrict__ x, const void* __restrict__ mask_x,
    const void* __restrict__ w_ih_l1,
    char* __restrict__ xs, char* __restrict__ ws1, int have_ws1)
{
    const bool isbf = (*flag != 0);
    const int i = blockIdx.x * 256 + threadIdx.x;
    if (i < 1048576) {                       // 32 b * 512 t * 64 chunks
        const int b = i >> 15;
        const int rem = i & 32767;
        const int t = rem >> 6;
        const int c = rem & 63;
        const size_t xoff = ((size_t)(b * 512 + t)) * 512 + c * 8;
        if (isbf) {
            const ushort_t* X = (const ushort_t*)x;
            const ushort_t* M = (const ushort_t*)mask_x + b * 512 + c * 8;
            short8 o;
#pragma unroll
            for (int e = 0; e < 8; ++e) o[e] = (short)f2b(b2f(X[xoff + e]) * b2f(M[e]));
            *(short8*)(xs + ((size_t)t * 32 + b) * 1024 + c * 16) = o;
        } else {
            float v[8], m[8];
            load8f((const float*)x + xoff, v);
            load8f((const float*)mask_x + b * 512 + c * 8, m);
#pragma unroll
            for (int e = 0; e < 8; ++e) v[e] *= m[e];
            short8 hi, lo; split8(v, hi, lo);
            char* p = xs + ((size_t)t * 32 + b) * 2048 + c * 32;
            *(short8*)p = hi; *(short8*)(p + 16) = lo;
        }
    } else if (have_ws1 && !isbf) {          // 4096 rows * 128 chunks
        const int jj = i - 1048576;
        const int row = jj >> 7;
        const int c = jj & 127;
        float v[8];
        load8f((const float*)w_ih_l1 + (size_t)row * 1024 + c * 8, v);
        short8 hi, lo; split8(v, hi, lo);
        char* p = ws1 + (size_t)row * 4096 + c * 32;
        *(short8*)p = hi; *(short8*)(p + 16) = lo;
    }
}

// Persistent per-layer LSTM: 64 blocks (32 per direction) x 256 thr, all 512
// timesteps in one launch. NO cache-wide fences: h is exchanged through the
// coherent LLC with per-op sc0/sc1 loads/stores; counter handshake is relaxed
// agent atomics ordered by vmcnt drain. Everything else stays L2-resident.
// h buffer layout per (parity,dir): 32 rows x 2048B; row = [hi plane 1024B |
// lo plane 1024B] of 512 bf16 each.
template <int LAYER>
__global__ __launch_bounds__(256, 1) void lstm_phase(
    const int* __restrict__ flag,
    const char* __restrict__ xs,     // L0: XS (in d_out); L1: OS (in ws)
    char* __restrict__ os,           // L0 output region (ws); unused for L1
    const char* __restrict__ ws1c,   // pre-split W_ih_l1 (or null)
    char* __restrict__ hs,           // h double buffer, 4 * 64KB
    unsigned int* cnt,               // arrival counters, cnt[0] / cnt[32]
    const void* __restrict__ w_ih, const void* __restrict__ w_hh,
    const void* __restrict__ bias, const void* __restrict__ mask_h,
    const void* __restrict__ mask_out, void* __restrict__ dout,
    int os4_host, int have_ws1, int write_hn)
{
    __shared__ __align__(16) char smem[65536];           // h tile (swizzled)
    float (*gbuf)[32][16] = (float (*)[32][16])smem;     // aliased: used after h reads
    const int d    = blockIdx.x >> 5;
    const int j0   = (blockIdx.x & 31) << 4;
    const int tid  = threadIdx.x;
    const int lane = tid & 63;
    const int q    = tid >> 6;
    const int n16  = lane & 15;
    const int quad = lane >> 4;
    const int koff = quad * 8;
    const int g    = q * 512 + j0 + n16;
    const bool isbf = (*flag != 0);
    const bool os4  = (!isbf) && (os4_host != 0);
    unsigned int* mycnt = cnt + d * 32;

    // ---- one-time: W_hh slice -> registers (16 chunks hi/lo) ----
    short8 whh_h[16], whh_l[16];
    if (isbf) {
        const ushort_t* W = (const ushort_t*)w_hh + ((size_t)(d * 2048 + g)) * 512 + koff;
#pragma unroll
        for (int ki = 0; ki < 16; ++ki) {
            whh_h[ki] = *(const short8*)(W + ki * 32);
            whh_l[ki] = short8{0,0,0,0,0,0,0,0};
        }
    } else {
        const float* W = (const float*)w_hh + ((size_t)(d * 2048 + g)) * 512 + koff;
#pragma unroll
        for (int ki = 0; ki < 16; ++ki) {
            float w8[8]; load8f(W + ki * 32, w8);
            split8(w8, whh_h[ki], whh_l[ki]);
        }
    }
    // ---- one-time (L0): W_ih slice -> registers ----
    short8 wih_h[16], wih_l[16];
    if constexpr (LAYER == 0) {
        if (isbf) {
            const ushort_t* W = (const ushort_t*)w_ih + ((size_t)(d * 2048 + g)) * 512 + koff;
#pragma unroll
            for (int ki = 0; ki < 16; ++ki) {
                wih_h[ki] = *(const short8*)(W + ki * 32);
                wih_l[ki] = short8{0,0,0,0,0,0,0,0};
            }
        } else {
            const float* W = (const float*)w_ih + ((size_t)(d * 2048 + g)) * 512 + koff;
#pragma unroll
            for (int ki = 0; ki < 16; ++ki) {
                float w8[8]; load8f(W + ki * 32, w8);
                split8(w8, wih_h[ki], wih_l[ki]);
            }
        }
    }

    // ---- one-time: biases / masks for the epilogue -> registers ----
    float pbi[2], pbf[2], pbg[2], pbo[2], pmh[2], pmo[2];
#pragma unroll
    for (int rep = 0; rep < 2; ++rep) {
        const int idx = tid + rep * 256;
        const int b = idx >> 4;
        const int j = j0 + (idx & 15);
        if (isbf) {
            const ushort_t* BI = (const ushort_t*)bias;
            const ushort_t* MH = (const ushort_t*)mask_h + LAYER * 16384;
            pbi[rep] = b2f(BI[d * 2048 + j]);        pbf[rep] = b2f(BI[d * 2048 + 512 + j]);
            pbg[rep] = b2f(BI[d * 2048 + 1024 + j]); pbo[rep] = b2f(BI[d * 2048 + 1536 + j]);
            pmh[rep] = b2f(MH[b * 512 + j]);
            if constexpr (LAYER == 0) pmo[rep] = b2f(((const ushort_t*)mask_out)[b * 1024 + d * 512 + j]);
            else pmo[rep] = 0.f;
        } else {
            const float* BI = (const float*)bias;
            const float* MH = (const float*)mask_h + LAYER * 16384;
            pbi[rep] = BI[d * 2048 + j];        pbf[rep] = BI[d * 2048 + 512 + j];
            pbg[rep] = BI[d * 2048 + 1024 + j]; pbo[rep] = BI[d * 2048 + 1536 + j];
            pmh[rep] = MH[b * 512 + j];
            if constexpr (LAYER == 0) pmo[rep] = ((const float*)mask_out)[b * 1024 + d * 512 + j];
            else pmo[rep] = 0.f;
        }
    }
    float creg[2] = {0.f, 0.f};   // cell state lives in registers

    for (int s = 0; s < 512; ++s) {
        const int t = d ? (511 - s) : s;
        floatx4 acc0 = {0.f, 0.f, 0.f, 0.f};
        floatx4 acc1 = {0.f, 0.f, 0.f, 0.f};

        // ================= x-part (independent of h; before barrier) =========
        if constexpr (LAYER == 0) {
            if (isbf) {
                const char* xb0 = xs + ((size_t)t * 32 + n16) * 1024 + quad * 16;
                const char* xb1 = xs + ((size_t)t * 32 + n16 + 16) * 1024 + quad * 16;
#pragma unroll
                for (int ki = 0; ki < 16; ++ki) {
                    short8 a0 = *(const short8*)(xb0 + ki * 64);
                    short8 a1 = *(const short8*)(xb1 + ki * 64);
                    acc0 = mfma16(a0, wih_h[ki], acc0);
                    acc1 = mfma16(a1, wih_h[ki], acc1);
                }
            } else {
                const char* xb0 = xs + ((size_t)t * 32 + n16) * 2048 + quad * 32;
                const char* xb1 = xs + ((size_t)t * 32 + n16 + 16) * 2048 + quad * 32;
#pragma unroll
                for (int ki = 0; ki < 16; ++ki) {
                    short8 a0h = *(const short8*)(xb0 + ki * 128);
                    short8 a0l = *(const short8*)(xb0 + ki * 128 + 16);
                    short8 a1h = *(const short8*)(xb1 + ki * 128);
                    short8 a1l = *(const short8*)(xb1 + ki * 128 + 16);
                    acc0 = mfma16(a0h, wih_h[ki], acc0);
                    acc0 = mfma16(a0l, wih_h[ki], acc0);
                    acc0 = mfma16(a0h, wih_l[ki], acc0);
                    acc1 = mfma16(a1h, wih_h[ki], acc1);
                    acc1 = mfma16(a1l, wih_h[ki], acc1);
                    acc1 = mfma16(a1h, wih_l[ki], acc1);
                }
            }
        } else {
            const size_t wrow = (size_t)d * 2048 + g;
            if (isbf) {
                const ushort_t* W = (const ushort_t*)w_ih + wrow * 1024 + koff;
                const char* ab0 = xs + ((size_t)t * 32 + n16) * 2048 + quad * 16;
                const char* ab1 = xs + ((size_t)t * 32 + n16 + 16) * 2048 + quad * 16;
#pragma unroll 4
                for (int ki = 0; ki < 32; ++ki) {
                    short8 a0 = *(const short8*)(ab0 + ki * 64);
                    short8 a1 = *(const short8*)(ab1 + ki * 64);
                    short8 bh = *(const short8*)(W + ki * 32);
                    acc0 = mfma16(a0, bh, acc0);
                    acc1 = mfma16(a1, bh, acc1);
                }
            } else if (have_ws1) {
                const char* wb = ws1c + wrow * 4096 + quad * 32;
                if (os4) {
                    const char* ab0 = xs + ((size_t)t * 32 + n16) * 4096 + quad * 32;
                    const char* ab1 = xs + ((size_t)t * 32 + n16 + 16) * 4096 + quad * 32;
#pragma unroll 4
                    for (int ki = 0; ki < 32; ++ki) {
                        short8 bh  = *(const short8*)(wb + ki * 128);
                        short8 bl  = *(const short8*)(wb + ki * 128 + 16);
                        short8 a0h = *(const short8*)(ab0 + ki * 128);
                        short8 a0l = *(const short8*)(ab0 + ki * 128 + 16);
                        short8 a1h = *(const short8*)(ab1 + ki * 128);
                        short8 a1l = *(const short8*)(ab1 + ki * 128 + 16);
                        acc0 = mfma16(a0h, bh, acc0);
                        acc0 = mfma16(a0l, bh, acc0);
                        acc0 = mfma16(a0h, bl, acc0);
                        acc1 = mfma16(a1h, bh, acc1);
                        acc1 = mfma16(a1l, bh, acc1);
                        acc1 = mfma16(a1h, bl, acc1);
                    }
                } else {    // compact OS: a_lo == 0 exactly -> skip its MFMA
                    const char* ab0 = xs + ((size_t)t * 32 + n16) * 2048 + quad * 16;
                    const char* ab1 = xs + ((size_t)t * 32 + n16 + 16) * 2048 + quad * 16;
#pragma unroll 4
                    for (int ki = 0; ki < 32; ++ki) {
                        short8 bh = *(const short8*)(wb + ki * 128);
                        short8 bl = *(const short8*)(wb + ki * 128 + 16);
                        short8 a0 = *(const short8*)(ab0 + ki * 64);
                        short8 a1 = *(const short8*)(ab1 + ki * 64);
                        acc0 = mfma16(a0, bh, acc0);
                        acc0 = mfma16(a0, bl, acc0);
                        acc1 = mfma16(a1, bh, acc1);
                        acc1 = mfma16(a1, bl, acc1);
                    }
                }
            } else {        // floor tier: split W_ih_l1 in-loop (slow, rare)
                const float* wf = (const float*)w_ih + wrow * 1024 + koff;
                if (os4) {
                    const char* ab0 = xs + ((size_t)t * 32 + n16) * 4096 + quad * 32;
                    const char* ab1 = xs + ((size_t)t * 32 + n16 + 16) * 4096 + quad * 32;
#pragma unroll 4
                    for (int ki = 0; ki < 32; ++ki) {
                        float w8[8]; load8f(wf + ki * 32, w8);
                        short8 bh, bl; split8(w8, bh, bl);
                        short8 a0h = *(const short8*)(ab0 + ki * 128);
                        short8 a0l = *(const short8*)(ab0 + ki * 128 + 16);
                        short8 a1h = *(const short8*)(ab1 + ki * 128);
                        short8 a1l = *(const short8*)(ab1 + ki * 128 + 16);
                        acc0 = mfma16(a0h, bh, acc0);
                        acc0 = mfma16(a0l, bh, acc0);
                        acc0 = mfma16(a0h, bl, acc0);
                        acc1 = mfma16(a1h, bh, acc1);
                        acc1 = mfma16(a1l, bh, acc1);
                        acc1 = mfma16(a1h, bl, acc1);
                    }
                } else {
                    const char* ab0 = xs + ((size_t)t * 32 + n16) * 2048 + quad * 16;
                    const char* ab1 = xs + ((size_t)t * 32 + n16 + 16) * 2048 + quad * 16;
#pragma unroll 4
                    for (int ki = 0; ki < 32; ++ki) {
                        float w8[8]; load8f(wf + ki * 32, w8);
                        short8 bh, bl; split8(w8, bh, bl);
                        short8 a0 = *(const short8*)(ab0 + ki * 64);
                        short8 a1 = *(const short8*)(ab1 + ki * 64);
                        acc0 = mfma16(a0, bh, acc0);
                        acc0 = mfma16(a0, bl, acc0);
                        acc1 = mfma16(a1, bh, acc1);
                        acc1 = mfma16(a1, bl, acc1);
                    }
                }
            }
        }

        // ================= wait for h(s-1) from all 32 sibling blocks ========
        if (tid == 0) {
            const unsigned int target = 32u * (unsigned int)s;
            while (__hip_atomic_load(mycnt, __ATOMIC_RELAXED, __HIP_MEMORY_SCOPE_AGENT) < target) { }
        }
        __syncthreads();
        __builtin_amdgcn_sched_barrier(0);

        // ================= stage h tile (LLC-coherent) -> LDS ================
        {
            const char* hr = hs + (size_t)((s & 1) * 2 + d) * 65536;
            if (isbf) {                       // hi planes only: 32 rows x 1024B
                unsigned long long tmp[16];
#pragma unroll
                for (int c = 0; c < 16; ++c) {
                    const int uidx = c * 256 + tid;
                    const int row = uidx >> 7;
                    const int inrow = (uidx & 127) * 8;
                    asm volatile("global_load_dwordx2 %0, %1, off sc0 sc1"
                                 : "=v"(tmp[c]) : "v"(hr + (size_t)row * 2048 + inrow));
                }
                asm volatile("s_waitcnt vmcnt(0)" ::: "memory");
                __builtin_amdgcn_sched_barrier(0);
#pragma unroll
                for (int c = 0; c < 16; ++c) {
                    const int uidx = c * 256 + tid;
                    const int row = uidx >> 7;
                    const int inrow = (uidx & 127) * 8;
                    *(unsigned long long*)(smem + row * 2048 + (inrow ^ ((row & 7) << 4))) = tmp[c];
                }
            } else {                          // full rows: 32 x 2048B
#pragma unroll
                for (int half = 0; half < 2; ++half) {
                    unsigned long long tmp[16];
#pragma unroll
                    for (int c = 0; c < 16; ++c) {
                        const int byte = (half * 4096 + c * 256 + tid) * 8;
                        asm volatile("global_load_dwordx2 %0, %1, off sc0 sc1"
                                     : "=v"(tmp[c]) : "v"(hr + byte));
                    }
                    asm volatile("s_waitcnt vmcnt(0)" ::: "memory");
                    __builtin_amdgcn_sched_barrier(0);
#pragma unroll
                    for (int c = 0; c < 16; ++c) {
                        const int byte = (half * 4096 + c * 256 + tid) * 8;
                        const int row = byte >> 11;
                        const int inrow = byte & 2047;
                        *(unsigned long long*)(smem + row * 2048 + (inrow ^ ((row & 7) << 4))) = tmp[c];
                    }
                }
            }
        }
        __syncthreads();

        // ================= h-part (register-resident W_hh, LDS A-frags) ======
        {
            const char* hb0 = smem + n16 * 2048;
            const char* hb1 = smem + (n16 + 16) * 2048;
            const int sw = (n16 & 7) << 4;
            if (isbf) {
#pragma unroll
                for (int ki = 0; ki < 16; ++ki) {
                    const int o = (ki * 64 + quad * 16) ^ sw;
                    short8 a0 = *(const short8*)(hb0 + o);
                    short8 a1 = *(const short8*)(hb1 + o);
                    acc0 = mfma16(a0, whh_h[ki], acc0);
                    acc1 = mfma16(a1, whh_h[ki], acc1);
                }
            } else {
#pragma unroll
                for (int ki = 0; ki < 16; ++ki) {
                    const int o = (ki * 64 + quad * 16) ^ sw;
                    short8 a0h = *(const short8*)(hb0 + o);
                    short8 a0l = *(const short8*)(hb0 + 1024 + o);
                    short8 a1h = *(const short8*)(hb1 + o);
                    short8 a1l = *(const short8*)(hb1 + 1024 + o);
                    acc0 = mfma16(a0h, whh_h[ki], acc0);
                    acc0 = mfma16(a0l, whh_h[ki], acc0);
                    acc0 = mfma16(a0h, whh_l[ki], acc0);
                    acc1 = mfma16(a1h, whh_h[ki], acc1);
                    acc1 = mfma16(a1l, whh_h[ki], acc1);
                    acc1 = mfma16(a1h, whh_l[ki], acc1);
                }
            }
        }
        __syncthreads();          // all hlds reads done before gbuf overwrites it

        // ================= gate exchange + epilogue ==========================
#pragma unroll
        for (int r = 0; r < 4; ++r) {
            gbuf[q][quad * 4 + r][n16]      = acc0[r];
            gbuf[q][16 + quad * 4 + r][n16] = acc1[r];
        }
        __syncthreads();

        char* hwbase = hs + (size_t)(((s + 1) & 1) * 2 + d) * 65536;
#pragma unroll
        for (int rep = 0; rep < 2; ++rep) {
            const int idx = tid + rep * 256;
            const int b = idx >> 4;
            const int n = idx & 15;
            const int j = j0 + n;
            const int jg = d * 512 + j;
            float ig = gbuf[0][b][n] + pbi[rep];
            float fg = gbuf[1][b][n] + pbf[rep];
            float gg = gbuf[2][b][n] + pbg[rep];
            float og = gbuf[3][b][n] + pbo[rep];
            float si = 1.f / (1.f + expf(-ig));
            float sf = 1.f / (1.f + expf(-fg));
            float so = 1.f / (1.f + expf(-og));
            float cn = sf * creg[rep] + si * tanhf(gg);
            float h  = so * tanhf(cn);
            creg[rep] = cn;

            float hm = h * pmh[rep];
            char* hw = hwbase + (size_t)b * 2048 + j * 2;
            ushort_t hhi = f2b(hm);
            store2_cc(hw, hhi);
            if (!isbf) store2_cc(hw + 1024, f2b(hm - b2f(hhi)));

            if constexpr (LAYER == 0) {
                float ho = h * pmo[rep];
                if (os4) {
                    char* op = os + ((size_t)t * 32 + b) * 4096 + (jg >> 3) * 32 + (jg & 7) * 2;
                    ushort_t ohi = f2b(ho);
                    *(ushort_t*)op        = ohi;
                    *(ushort_t*)(op + 16) = f2b(ho - b2f(ohi));
                } else {
                    *(ushort_t*)(os + ((size_t)t * 32 + b) * 2048 + (size_t)jg * 2) = f2b(ho);
                }
            } else {
                size_t o1 = ((size_t)b * 512 + t) * 1024 + jg;
                if (isbf) ((ushort_t*)dout)[o1] = f2b(h);
                else      ((float*)dout)[o1]    = h;
            }
            if (s == 511 && write_hn) {
                size_t hnidx = 16777216u + (size_t)((LAYER * 2 + d) * 32 + b) * 512 + j;
                if (isbf) { ((ushort_t*)dout)[hnidx] = f2b(h); ((ushort_t*)dout)[hnidx + 65536] = f2b(cn); }
                else      { ((float*)dout)[hnidx]    = h;      ((float*)dout)[hnidx + 65536]    = cn; }
            }
        }
        // drain this wave's h stores to the LLC, then signal
        asm volatile("s_waitcnt vmcnt(0)" ::: "memory");
        __syncthreads();
        if (tid == 0)
            __hip_atomic_fetch_add(mycnt, 1u, __ATOMIC_RELAXED, __HIP_MEMORY_SCOPE_AGENT);
    }
}

extern "C" void kernel_launch(void* const* d_in, const int* in_sizes, int n_in,
                              void* d_out, int out_size, void* d_ws, size_t ws_size,
                              hipStream_t stream) {
    char* ws = (char*)d_ws;
    const size_t HSB = 262144;   // h double-buffer: [2 par][2 d] * 64KB
    // ws layout: [OS (67.1MB full | 33.5MB compact)][WS1 16.8MB?][HS][cnt 256][flag 4]
    int os4 = 0, hws1 = 0;
    size_t osb;
    if      (ws_size >= 67108864ull + 16777216ull + HSB + 512) { os4 = 1; hws1 = 1; osb = 67108864ull; }
    else if (ws_size >= 67108864ull + HSB + 512)               { os4 = 1; hws1 = 0; osb = 67108864ull; }
    else if (ws_size >= 33554432ull + 16777216ull + HSB + 512) { os4 = 0; hws1 = 1; osb = 33554432ull; }
    else                                                       { os4 = 0; hws1 = 0; osb = 33554432ull; }
    char* ws1 = ws + osb;
    char* hs  = ws1 + (hws1 ? 16777216 : 0);
    unsigned int* cnt = (unsigned int*)(hs + HSB);
    int* flag = (int*)(hs + HSB + 256);
    int write_hn = (out_size >= 16908288) ? 1 : 0;

    // dtype from input byte size when unambiguous; sniff otherwise.
    int hb = -1;
    if (in_sizes && n_in > 0) {
        if (in_sizes[0] == 33554432) hb = 0;        // f32 x [32,512,512]
        else if (in_sizes[0] == 16777216) hb = 1;   // bf16
    }

    hipMemsetAsync(hs, 0, HSB + 512, stream);       // h=0, cnt=0, flag=0
    if (hb == 1)       hipMemsetAsync(flag, 1, 4, stream);   // nonzero -> bf16
    else if (hb == -1) detect_dtype<<<1, 256, 0, stream>>>((const unsigned int*)d_in[0], flag);

    // Pre-split masked X (scratch in d_out) and W_ih_l1 (ws).
    prep<<<6144, 256, 0, stream>>>(flag, d_in[0], d_in[1], d_in[7],
                                   (char*)d_out, hws1 ? ws1 : nullptr, hws1);

    // Layer 0: persistent, 512 steps with fence-free device handshake.
    lstm_phase<0><<<64, 256, 0, stream>>>(flag, (const char*)d_out, ws, nullptr,
        hs, cnt, d_in[4], d_in[5], d_in[6], d_in[3], d_in[2], d_out,
        os4, hws1, write_hn);

    hipMemsetAsync(hs, 0, HSB + 256, stream);       // reset h + cnt, keep flag

    // Layer 1: persistent; reads OS (+ pre-split W_ih_l1), writes d_out.
    lstm_phase<1><<<64, 256, 0, stream>>>(flag, (const char*)ws, ws, hws1 ? ws1 : nullptr,
        hs, cnt, d_in[7], d_in[8], d_in[9], d_in[3], nullptr, d_out,
        os4, hws1, write_hn);
}

// Round 3
// 8606.771 us; speedup vs baseline: 4.1862x; 2.8514x over previous
//
#include <hip/hip_runtime.h>
#include <math.h>

typedef unsigned short ushort_t;
typedef short short8 __attribute__((ext_vector_type(8)));
typedef float floatx4 __attribute__((ext_vector_type(4)));
typedef float float4v __attribute__((ext_vector_type(4)));
typedef unsigned int uint4v __attribute__((ext_vector_type(4)));

__device__ __forceinline__ float b2f(ushort_t u) {
    union { unsigned int i; float f; } v; v.i = ((unsigned int)u) << 16; return v.f;
}
__device__ __forceinline__ ushort_t f2b(float f) {
    union { float f; unsigned int i; } v; v.f = f;
    unsigned int x = v.i;
    return (ushort_t)((x + 0x7fffu + ((x >> 16) & 1u)) >> 16);  // RNE
}
__device__ __forceinline__ void split8(const float* v, short8& hi, short8& lo) {
#pragma unroll
    for (int e = 0; e < 8; ++e) {
        ushort_t h = f2b(v[e]);
        hi[e] = (short)h;
        lo[e] = (short)f2b(v[e] - b2f(h));
    }
}
__device__ __forceinline__ void load8f(const float* p, float* v) {
    *(float4v*)(v)     = *(const float4v*)(p);
    *(float4v*)(v + 4) = *(const float4v*)(p + 4);
}
__device__ __forceinline__ floatx4 mfma16(short8 a, short8 b, floatx4 c) {
    return __builtin_amdgcn_mfma_f32_16x16x32_bf16(a, b, c, 0, 0, 0);
}
// Coherent (LLC) ops: bypass L1/L2 so remote XCDs see/read fresh data.
__device__ __forceinline__ void store2_cc(void* p, ushort_t v) {
    asm volatile("global_store_short %0, %1, off sc0 sc1"
                 :: "v"(p), "v"((unsigned int)v) : "memory");
}

// Classify input encoding (fallback when in_sizes doesn't resolve it).
__global__ void detect_dtype(const unsigned int* __restrict__ x, int* __restrict__ flag) {
    __shared__ int cnt;
    if (threadIdx.x == 0) cnt = 0;
    __syncthreads();
    int c = 0;
#pragma unroll
    for (int i = 0; i < 8; ++i) {
        unsigned int w = x[threadIdx.x * 8 + i];
        unsigned int e = (w >> 7) & 0xFFu;
        if (e >= 100u && e <= 140u) ++c;
    }
    atomicAdd(&cnt, c);
    __syncthreads();
    if (threadIdx.x == 0) *flag = (cnt > 1024) ? 1 : 0;   // 1 = bf16, 0 = f32
}

// One-time pre-split of masked X into XS (d_out scratch).
// f32: interleaved [hi8|lo8] 32B chunks, row (t*32+b)*2048. bf16: 16B chunks, *1024.
__global__ __launch_bounds__(256) void prep(
    const int* __restrict__ flag,
    const void* __restrict__ x, const void* __restrict__ mask_x,
    char* __restrict__ xs)
{
    const bool isbf = (*flag != 0);
    const int i = blockIdx.x * 256 + threadIdx.x;       // 1048576 total
    const int b = i >> 15;
    const int rem = i & 32767;
    const int t = rem >> 6;
    const int c = rem & 63;
    const size_t xoff = ((size_t)(b * 512 + t)) * 512 + c * 8;
    if (isbf) {
        const ushort_t* X = (const ushort_t*)x;
        const ushort_t* M = (const ushort_t*)mask_x + b * 512 + c * 8;
        short8 o;
#pragma unroll
        for (int e = 0; e < 8; ++e) o[e] = (short)f2b(b2f(X[xoff + e]) * b2f(M[e]));
        *(short8*)(xs + ((size_t)t * 32 + b) * 1024 + c * 16) = o;
    } else {
        float v[8], m[8];
        load8f((const float*)x + xoff, v);
        load8f((const float*)mask_x + b * 512 + c * 8, m);
#pragma unroll
        for (int e = 0; e < 8; ++e) v[e] *= m[e];
        short8 hi, lo; split8(v, hi, lo);
        char* p = xs + ((size_t)t * 32 + b) * 2048 + c * 32;
        *(short8*)p = hi; *(short8*)(p + 16) = lo;
    }
}

// LDS swizzle: spreads rows and 64B-segments across banks. Pure fn of (row,o).
__device__ __forceinline__ int lds_swz(int row, int o) {
    return o ^ ((row & 7) << 4) ^ (((o >> 6) & 7) << 4);
}

// Persistent LSTM layer. 128 blocks x 512 thr. Block = (dir, j-tile, m-half);
// wave = (gate q, K-half kh). ALL weights register-resident (hi/lo split).
// Per step: x-part from L2 (pre-poll), h staged LLC->LDS (32KB), K-halves
// reduced via LDS, epilogue by 256 threads, h broadcast via LLC sc0sc1.
template <int LAYER>
__global__ __launch_bounds__(512, 2) void lstm_phase(
    const int* __restrict__ flag,
    const char* __restrict__ xs,     // L0: XS (d_out scratch); L1: OS (ws)
    char* __restrict__ os,           // L0 writes OS here
    char* __restrict__ hs,           // h bufs: [par][dir]*64KB: hi[32][512]2B, lo +32768
    unsigned int* cnt,               // cnt[0]=dir0, cnt[16]=dir1
    const void* __restrict__ w_ih, const void* __restrict__ w_hh,
    const void* __restrict__ bias, const void* __restrict__ mask_h,
    const void* __restrict__ mask_out, void* __restrict__ dout,
    int os4_host, int write_hn)
{
    __shared__ __align__(16) char smem[40960];   // h tile 32KB + gbuf 8KB
    float* gb = (float*)(smem + 32768);
    const int dir  = blockIdx.x >> 6;
    const int b6   = blockIdx.x & 63;
    const int jt   = b6 & 31;
    const int m    = b6 >> 5;
    const int j0   = jt << 4;
    const int tid  = threadIdx.x;
    const int w    = tid >> 6;
    const int q    = w & 3;          // gate
    const int kh   = w >> 2;         // K-half
    const int lane = tid & 63;
    const int n16  = lane & 15;
    const int quad = lane >> 4;
    const bool isbf = (*flag != 0);
    const bool os4  = (!isbf) && (os4_host != 0);
    unsigned int* mycnt = cnt + dir * 16;
    constexpr int KI = (LAYER == 0) ? 512 : 1024;   // ih K total
    constexpr int NI = KI / 64;                     // ih tiles per half: 8 / 16
    constexpr int NH = 8;                           // hh tiles per half
    const int gq = q * 512 + j0 + n16;              // gate row

    // ---- one-time: weights -> registers (hi/lo) ----
    short8 wih_h[NI], wih_l[NI], whh_h[NH], whh_l[NH];
    if (isbf) {
        const ushort_t* WI = (const ushort_t*)w_ih + ((size_t)(dir * 2048 + gq)) * KI + kh * (KI / 2) + quad * 8;
        const ushort_t* WH = (const ushort_t*)w_hh + ((size_t)(dir * 2048 + gq)) * 512 + kh * 256 + quad * 8;
#pragma unroll
        for (int ki = 0; ki < NI; ++ki) { wih_h[ki] = *(const short8*)(WI + ki * 32); wih_l[ki] = short8{0,0,0,0,0,0,0,0}; }
#pragma unroll
        for (int ki = 0; ki < NH; ++ki) { whh_h[ki] = *(const short8*)(WH + ki * 32); whh_l[ki] = short8{0,0,0,0,0,0,0,0}; }
    } else {
        const float* WI = (const float*)w_ih + ((size_t)(dir * 2048 + gq)) * KI + kh * (KI / 2) + quad * 8;
        const float* WH = (const float*)w_hh + ((size_t)(dir * 2048 + gq)) * 512 + kh * 256 + quad * 8;
#pragma unroll
        for (int ki = 0; ki < NI; ++ki) { float w8[8]; load8f(WI + ki * 32, w8); split8(w8, wih_h[ki], wih_l[ki]); }
#pragma unroll
        for (int ki = 0; ki < NH; ++ki) { float w8[8]; load8f(WH + ki * 32, w8); split8(w8, whh_h[ki], whh_l[ki]); }
    }

    // ---- one-time: epilogue constants (tid<256 owns one (b,j) cell) ----
    float pbi = 0.f, pbf = 0.f, pbg = 0.f, pbo = 0.f, pmh = 0.f, pmo = 0.f;
    int eb = 0, en = 0, ej = 0, erow = 0;
    if (tid < 256) {
        eb = tid >> 4; en = tid & 15; ej = j0 + en; erow = m * 16 + eb;
        if (isbf) {
            const ushort_t* BI = (const ushort_t*)bias;
            const ushort_t* MH = (const ushort_t*)mask_h + LAYER * 16384;
            pbi = b2f(BI[dir * 2048 + ej]);        pbf = b2f(BI[dir * 2048 + 512 + ej]);
            pbg = b2f(BI[dir * 2048 + 1024 + ej]); pbo = b2f(BI[dir * 2048 + 1536 + ej]);
            pmh = b2f(MH[erow * 512 + ej]);
            if (LAYER == 0) pmo = b2f(((const ushort_t*)mask_out)[erow * 1024 + dir * 512 + ej]);
        } else {
            const float* BI = (const float*)bias;
            const float* MH = (const float*)mask_h + LAYER * 16384;
            pbi = BI[dir * 2048 + ej];        pbf = BI[dir * 2048 + 512 + ej];
            pbg = BI[dir * 2048 + 1024 + ej]; pbo = BI[dir * 2048 + 1536 + ej];
            pmh = MH[erow * 512 + ej];
            if (LAYER == 0) pmo = ((const float*)mask_out)[erow * 1024 + dir * 512 + ej];
        }
    }
    float creg = 0.f;                // cell state: one value per epilogue thread

    for (int s = 0; s < 512; ++s) {
        const int t = dir ? (511 - s) : s;
        floatx4 acc = {0.f, 0.f, 0.f, 0.f};

        // ============ x-part (no h dependence; before the poll) ============
        if (isbf) {
            const int stride = (LAYER == 0) ? 1024 : 2048;
            const char* xb = xs + ((size_t)t * 32 + m * 16 + n16) * stride + (kh * NI * 4 + quad) * 16;
#pragma unroll
            for (int ki = 0; ki < NI; ++ki) {
                short8 a = *(const short8*)(xb + ki * 64);
                acc = mfma16(a, wih_h[ki], acc);
            }
        } else if (LAYER == 1 && !os4) {   // compact OS: a_lo==0 exactly
            const char* xb = xs + ((size_t)t * 32 + m * 16 + n16) * 2048 + (kh * 64 + quad) * 16;
#pragma unroll
            for (int ki = 0; ki < NI; ++ki) {
                short8 a = *(const short8*)(xb + ki * 64);
                acc = mfma16(a, wih_h[ki], acc);
                acc = mfma16(a, wih_l[ki], acc);
            }
        } else {                            // full hi/lo A
            const int stride = (LAYER == 0) ? 2048 : 4096;
            const char* xb = xs + ((size_t)t * 32 + m * 16 + n16) * stride + (kh * NI * 4 + quad) * 32;
#pragma unroll
            for (int ki = 0; ki < NI; ++ki) {
                short8 ah = *(const short8*)(xb + ki * 128);
                short8 al = *(const short8*)(xb + ki * 128 + 16);
                acc = mfma16(ah, wih_h[ki], acc);
                acc = mfma16(al, wih_h[ki], acc);
                acc = mfma16(ah, wih_l[ki], acc);
            }
        }

        // ============ wait: h(s-1) complete across this direction ==========
        if (tid == 0) {
            const unsigned int target = 64u * (unsigned int)s;
            while (__hip_atomic_load(mycnt, __ATOMIC_RELAXED, __HIP_MEMORY_SCOPE_AGENT) < target) { }
        }
        __syncthreads();
        __builtin_amdgcn_sched_barrier(0);

        // ============ stage h rows [m*16, m*16+16) LLC -> LDS ==============
        {
            const char* hr = hs + (size_t)((s & 1) * 2 + dir) * 65536;
            const int planes = isbf ? 1 : 2;
            if (tid < planes * 256) {
                const int p = tid >> 8, v = tid & 255;
                const int row = v >> 4, seg = v & 15;
                const char* gsrc = hr + p * 32768 + (size_t)(m * 16 + row) * 1024 + seg * 64;
                uint4v t0, t1, t2, t3;
                asm volatile("global_load_dwordx4 %0, %1, off sc0 sc1" : "=v"(t0) : "v"(gsrc));
                asm volatile("global_load_dwordx4 %0, %1, off sc0 sc1" : "=v"(t1) : "v"(gsrc + 16));
                asm volatile("global_load_dwordx4 %0, %1, off sc0 sc1" : "=v"(t2) : "v"(gsrc + 32));
                asm volatile("global_load_dwordx4 %0, %1, off sc0 sc1" : "=v"(t3) : "v"(gsrc + 48));
                asm volatile("s_waitcnt vmcnt(0)" ::: "memory");
                __builtin_amdgcn_sched_barrier(0);
                char* lbase = smem + p * 16384 + row * 1024;
                *(uint4v*)(lbase + lds_swz(row, seg * 64))      = t0;
                *(uint4v*)(lbase + lds_swz(row, seg * 64 + 16)) = t1;
                *(uint4v*)(lbase + lds_swz(row, seg * 64 + 32)) = t2;
                *(uint4v*)(lbase + lds_swz(row, seg * 64 + 48)) = t3;
            }
        }
        __syncthreads();

        // ============ h-part (register W_hh, LDS A-frags) ==================
        {
            const char* hrow = smem + n16 * 1024;
            if (isbf) {
#pragma unroll
                for (int ki = 0; ki < NH; ++ki) {
                    const int o = kh * 512 + ki * 64 + quad * 16;
                    short8 ah = *(const short8*)(hrow + lds_swz(n16, o));
                    acc = mfma16(ah, whh_h[ki], acc);
                }
            } else {
#pragma unroll
                for (int ki = 0; ki < NH; ++ki) {
                    const int o = kh * 512 + ki * 64 + quad * 16;
                    const int so = lds_swz(n16, o);
                    short8 ah = *(const short8*)(hrow + so);
                    short8 al = *(const short8*)(hrow + 16384 + so);
                    acc = mfma16(ah, whh_h[ki], acc);
                    acc = mfma16(al, whh_h[ki], acc);
                    acc = mfma16(ah, whh_l[ki], acc);
                }
            }
        }

        // ============ K-half reduction via LDS =============================
#pragma unroll
        for (int r = 0; r < 4; ++r)
            gb[((q * 2 + kh) * 16 + quad * 4 + r) * 16 + n16] = acc[r];
        __syncthreads();

        // ============ epilogue (tid<256) ===================================
        if (tid < 256) {
            const int cidx = eb * 16 + en;
            float ig = gb[0 * 256 + cidx] + gb[1 * 256 + cidx] + pbi;
            float fg = gb[2 * 256 + cidx] + gb[3 * 256 + cidx] + pbf;
            float gg = gb[4 * 256 + cidx] + gb[5 * 256 + cidx] + pbg;
            float og = gb[6 * 256 + cidx] + gb[7 * 256 + cidx] + pbo;
            float si = 1.f / (1.f + expf(-ig));
            float sf = 1.f / (1.f + expf(-fg));
            float so = 1.f / (1.f + expf(-og));
            float cn = sf * creg + si * tanhf(gg);
            float h  = so * tanhf(cn);
            creg = cn;

            const int jg = dir * 512 + ej;
            float hm = h * pmh;
            char* hw = hs + (size_t)(((s + 1) & 1) * 2 + dir) * 65536 + (size_t)erow * 1024 + ej * 2;
            ushort_t hhi = f2b(hm);
            store2_cc(hw, hhi);
            if (!isbf) store2_cc(hw + 32768, f2b(hm - b2f(hhi)));

            if constexpr (LAYER == 0) {
                float ho = h * pmo;
                if (os4) {
                    char* op = os + ((size_t)t * 32 + erow) * 4096 + (jg >> 3) * 32 + (jg & 7) * 2;
                    ushort_t ohi = f2b(ho);
                    *(ushort_t*)op        = ohi;
                    *(ushort_t*)(op + 16) = f2b(ho - b2f(ohi));
                } else {
                    *(ushort_t*)(os + ((size_t)t * 32 + erow) * 2048 + (size_t)jg * 2) = f2b(ho);
                }
            } else {
                size_t o1 = ((size_t)erow * 512 + t) * 1024 + jg;
                if (isbf) ((ushort_t*)dout)[o1] = f2b(h);
                else      ((float*)dout)[o1]    = h;
            }
            if (s == 511 && write_hn) {
                size_t hnidx = 16777216u + (size_t)((LAYER * 2 + dir) * 32 + erow) * 512 + ej;
                if (isbf) { ((ushort_t*)dout)[hnidx] = f2b(h); ((ushort_t*)dout)[hnidx + 65536] = f2b(cn); }
                else      { ((float*)dout)[hnidx]    = h;      ((float*)dout)[hnidx + 65536]    = cn; }
            }
        }
        // drain h stores to LLC, then signal this block's arrival
        asm volatile("s_waitcnt vmcnt(0)" ::: "memory");
        __syncthreads();
        if (tid == 0)
            __hip_atomic_fetch_add(mycnt, 1u, __ATOMIC_RELAXED, __HIP_MEMORY_SCOPE_AGENT);
    }
}

extern "C" void kernel_launch(void* const* d_in, const int* in_sizes, int n_in,
                              void* d_out, int out_size, void* d_ws, size_t ws_size,
                              hipStream_t stream) {
    char* ws = (char*)d_ws;
    const size_t HSB = 262144;   // h buffers: [2 par][2 dir] * 64KB
    // ws layout: [OS (67.1MB full | 33.5MB compact)][HS][cnt 256][flag 4]
    int os4 = (ws_size >= 67108864ull + HSB + 512) ? 1 : 0;
    size_t osb = os4 ? 67108864ull : 33554432ull;
    char* hs = ws + osb;
    unsigned int* cnt = (unsigned int*)(hs + HSB);
    int* flag = (int*)(hs + HSB + 256);
    int write_hn = (out_size >= 16908288) ? 1 : 0;

    // dtype from input byte size when unambiguous; sniff otherwise.
    int hb = -1;
    if (in_sizes && n_in > 0) {
        if (in_sizes[0] == 33554432) hb = 0;        // f32 x [32,512,512]
        else if (in_sizes[0] == 16777216) hb = 1;   // bf16
    }

    hipMemsetAsync(hs, 0, HSB + 512, stream);       // h=0, cnt=0, flag=0
    if (hb == 1)       hipMemsetAsync(flag, 1, 4, stream);   // nonzero -> bf16
    else if (hb == -1) detect_dtype<<<1, 256, 0, stream>>>((const unsigned int*)d_in[0], flag);

    // Pre-split masked X into d_out scratch (dead until L1 phase writes output).
    prep<<<4096, 256, 0, stream>>>(flag, d_in[0], d_in[1], (char*)d_out);

    // Layer 0: persistent, 512 steps, register-resident weights.
    lstm_phase<0><<<128, 512, 0, stream>>>(flag, (const char*)d_out, ws,
        hs, cnt, d_in[4], d_in[5], d_in[6], d_in[3], d_in[2], d_out,
        os4, write_hn);

    hipMemsetAsync(hs, 0, HSB + 256, stream);       // reset h + cnt, keep flag

    // Layer 1: persistent; reads OS, writes d_out.
    lstm_phase<1><<<128, 512, 0, stream>>>(flag, (const char*)ws, ws,
        hs, cnt, d_in[7], d_in[8], d_in[9], d_in[3], nullptr, d_out,
        os4, write_hn);
}